// Round 4
// baseline (1995.628 us; speedup 1.0000x reference)
//
#include <hip/hip_runtime.h>
#include <math.h>

typedef unsigned short u16;
typedef __attribute__((ext_vector_type(8))) short short8;
typedef __attribute__((ext_vector_type(4))) float f32x4;

#define EPS 1e-6f
#define AS1(p) ((const __attribute__((address_space(1))) void*)(p))
#define AS3(p) ((__attribute__((address_space(3))) void*)(p))

__device__ __forceinline__ unsigned f2bf(float f) {
  union { float f; unsigned u; } v; v.f = f;
  return (v.u + 0x7fffu + ((v.u >> 16) & 1u)) >> 16;
}
__device__ __forceinline__ float bf2f(u16 u) {
  union { unsigned u; float f; } v; v.u = ((unsigned)u) << 16; return v.f;
}

// ---------------- f32 -> bf16 convert (packed, 4/thread) ----------------
__global__ void k_cvt(const float* __restrict__ in, u16* __restrict__ out, int n) {
  int i = (blockIdx.x * blockDim.x + threadIdx.x) * 4;
  if (i >= n) return;
  float4 v = *(const float4*)(in + i);
  uint2 p;
  p.x = f2bf(v.x) | (f2bf(v.y) << 16);
  p.y = f2bf(v.z) | (f2bf(v.w) << 16);
  *(uint2*)(out + i) = p;
}

// ---------------- bf16 GEMM: C[M,N] = A[M,K] * B[N,K]^T ------------------
// 128x128 tile, BK=32, 4 waves (2x2 of 64x64), mfma 16x16x32, global_load_lds
// width 16, both-sides XOR swizzle of 16B chunks: chunk ^= (row>>1)&3.
// OB: write bf16 output instead of f32.
template <bool OB>
__global__ __launch_bounds__(256) void k_gemm_bt(const u16* __restrict__ A,
                                                 const u16* __restrict__ Bm,
                                                 void* __restrict__ Cv,
                                                 int M, int N, int K) {
  __shared__ short sA[4096];   // [128 rows][32 k] bf16 = 8KB
  __shared__ short sB[4096];
  const int tid = threadIdx.x;
  const int w = tid >> 6, lane = tid & 63;
  const int nbt = N >> 7;
  const int nwg = (M >> 7) * nbt;
  int bid = blockIdx.x;
  { // bijective XCD swizzle (all grids here are %8==0)
    int q = nwg >> 3;
    bid = (bid & 7) * q + (bid >> 3);
  }
  const int mt = bid / nbt, nt = bid - mt * nbt;
  const int m0 = mt << 7, n0 = nt << 7;
  const int wr = (w >> 1) << 6, wc = (w & 1) << 6;

  f32x4 acc[4][4] = {};

  int rdA[4], rdB[4];
#pragma unroll
  for (int i = 0; i < 4; ++i) {
    int row = wr + i * 16 + (lane & 15);
    rdA[i] = row * 64 + (((lane >> 4) ^ ((row >> 1) & 3)) << 4);
    int col = wc + i * 16 + (lane & 15);
    rdB[i] = col * 64 + (((lane >> 4) ^ ((col >> 1) & 3)) << 4);
  }
  int srow[2], scol[2];
#pragma unroll
  for (int j = 0; j < 2; ++j) {
    int y = (w * 2 + j) * 1024 + lane * 16;    // linear LDS byte this lane fills
    int rr = y >> 6;
    int cs = ((y >> 4) & 3) ^ ((rr >> 1) & 3); // inverse-swizzled source chunk
    srow[j] = rr;
    scol[j] = cs * 8;
  }
  const int nk = K >> 5;
  for (int kt = 0; kt < nk; ++kt) {
    const int k0 = kt << 5;
#pragma unroll
    for (int j = 0; j < 2; ++j) {
      const int ca = (w * 2 + j) * 1024;
      const u16* ga = A + (size_t)(m0 + srow[j]) * K + (k0 + scol[j]);
      __builtin_amdgcn_global_load_lds(AS1(ga), AS3((char*)sA + ca), 16, 0, 0);
      const u16* gb = Bm + (size_t)(n0 + srow[j]) * K + (k0 + scol[j]);
      __builtin_amdgcn_global_load_lds(AS1(gb), AS3((char*)sB + ca), 16, 0, 0);
    }
    __syncthreads();
    short8 af[4], bfr[4];
#pragma unroll
    for (int i = 0; i < 4; ++i) af[i] = *(const short8*)((const char*)sA + rdA[i]);
#pragma unroll
    for (int i = 0; i < 4; ++i) bfr[i] = *(const short8*)((const char*)sB + rdB[i]);
#pragma unroll
    for (int i = 0; i < 4; ++i)
#pragma unroll
      for (int j = 0; j < 4; ++j)
        acc[i][j] = __builtin_amdgcn_mfma_f32_16x16x32_bf16(af[i], bfr[j], acc[i][j], 0, 0, 0);
    __syncthreads();
  }
#pragma unroll
  for (int i = 0; i < 4; ++i)
#pragma unroll
    for (int j = 0; j < 4; ++j)
#pragma unroll
      for (int qe = 0; qe < 4; ++qe) {
        int mrow = m0 + wr + i * 16 + ((lane >> 4) << 2) + qe;
        int ncol = n0 + wc + j * 16 + (lane & 15);
        if (OB) ((u16*)Cv)[(size_t)mrow * N + ncol] = (u16)f2bf(acc[i][j][qe]);
        else    ((float*)Cv)[(size_t)mrow * N + ncol] = acc[i][j][qe];
      }
}

// ---------------- gates: a,b projections -> g, beta ----------------------
__global__ void k_gates(const float* __restrict__ hidden, const float* __restrict__ Wa,
                        const float* __restrict__ Wb, const float* __restrict__ Alog,
                        const float* __restrict__ dtb, float* __restrict__ g,
                        float* __restrict__ beta) {
  int t = blockIdx.x;              // token 0..4095
  int tid = threadIdx.x;           // 64: 0..31 -> a/g, 32..63 -> b/beta
  int h = tid & 31;
  const float4* h4 = (const float4*)(hidden + (size_t)t * 2048);
  const float4* w4 = (const float4*)((tid < 32 ? Wa : Wb) + (size_t)h * 2048);
  float acc = 0.f;
  for (int i = 0; i < 512; ++i) {
    float4 x = h4[i], y = w4[i];
    acc += x.x * y.x + x.y * y.y + x.z * y.z + x.w * y.w;
  }
  if (tid < 32) {
    float x = acc + dtb[h];
    float sp = x > 20.f ? x : log1pf(expf(x));
    g[t * 32 + h] = -expf(Alog[h]) * sp;
  } else {
    beta[t * 32 + h] = 1.f / (1.f + expf(-acc));
  }
}

// ---------------- causal conv(4) + SiLU + split + l2norm -----------------
// qkv bf16 in, qn/kn/vv bf16 out (packed). 8 channels per thread.
__global__ __launch_bounds__(256) void k_conv(const u16* __restrict__ qkv,
                                              const float* __restrict__ convw,
                                              u16* __restrict__ qnb, u16* __restrict__ knb,
                                              u16* __restrict__ vvb) {
  __shared__ float mix[4096];
  __shared__ float red[32][8];
  __shared__ float fac[32];
  const int t = blockIdx.x;
  const int s = t & 2047;
  const int tid = threadIdx.x;
  const u16* base = qkv + (size_t)t * 8192;
  // q,k channels 0..4095 -> LDS (need norms)
  for (int it = 0; it < 2; ++it) {
    int c0 = (it * 256 + tid) * 8;
    short8 x0 = *(const short8*)(base + c0);
    short8 x1 = (short8)0, x2 = (short8)0, x3 = (short8)0;
    if (s >= 1) x1 = *(const short8*)(base + c0 - 8192);
    if (s >= 2) x2 = *(const short8*)(base + c0 - 16384);
    if (s >= 3) x3 = *(const short8*)(base + c0 - 24576);
#pragma unroll
    for (int e = 0; e < 8; ++e) {
      int c = c0 + e;
      float4 wv = *(const float4*)(convw + c * 4);
      float a = bf2f((u16)x0[e]) * wv.w + bf2f((u16)x1[e]) * wv.z
              + bf2f((u16)x2[e]) * wv.y + bf2f((u16)x3[e]) * wv.x;
      mix[c] = a / (1.f + expf(-a));     // SiLU
    }
  }
  // v channels 4096..8191 -> straight to global (bf16 packed)
  for (int it = 0; it < 2; ++it) {
    int c0 = 4096 + (it * 256 + tid) * 8;
    short8 x0 = *(const short8*)(base + c0);
    short8 x1 = (short8)0, x2 = (short8)0, x3 = (short8)0;
    if (s >= 1) x1 = *(const short8*)(base + c0 - 8192);
    if (s >= 2) x2 = *(const short8*)(base + c0 - 16384);
    if (s >= 3) x3 = *(const short8*)(base + c0 - 24576);
    unsigned pk[4];
#pragma unroll
    for (int e2 = 0; e2 < 4; ++e2) {
      float vs[2];
#pragma unroll
      for (int u = 0; u < 2; ++u) {
        int e = e2 * 2 + u;
        float4 wv = *(const float4*)(convw + (c0 + e) * 4);
        float a = bf2f((u16)x0[e]) * wv.w + bf2f((u16)x1[e]) * wv.z
                + bf2f((u16)x2[e]) * wv.y + bf2f((u16)x3[e]) * wv.x;
        vs[u] = a / (1.f + expf(-a));
      }
      pk[e2] = f2bf(vs[0]) | (f2bf(vs[1]) << 16);
    }
    *(uint4*)(vvb + (size_t)t * 4096 + (c0 - 4096)) = *(uint4*)pk;
  }
  __syncthreads();
  { // per-head sumsq (32 head-slots x 8 partials of 16)
    int hh = tid >> 3, p = tid & 7;
    float ss2 = 0.f;
#pragma unroll
    for (int e = 0; e < 16; ++e) { float x = mix[hh * 128 + p * 16 + e]; ss2 += x * x; }
    red[hh][p] = ss2;
  }
  __syncthreads();
  if (tid < 32) {
    float ss2 = 0.f;
#pragma unroll
    for (int p = 0; p < 8; ++p) ss2 += red[tid][p];
    float inv = 1.f / fmaxf(sqrtf(ss2), EPS);
    if (tid < 16) inv *= 0.08838834764831845f;   // * DK^-0.5 for q heads
    fac[tid] = inv;
  }
  __syncthreads();
  // q -> qnb (it=0), k -> knb (it=1), bf16 packed
  for (int it = 0; it < 2; ++it) {
    int c0 = (it * 256 + tid) * 8;          // 0..2040 then 2048..4088
    float f = fac[c0 >> 7];
    unsigned pk[4];
#pragma unroll
    for (int e2 = 0; e2 < 4; ++e2) {
      float v0 = mix[c0 + e2 * 2] * f;
      float v1 = mix[c0 + e2 * 2 + 1] * f;
      pk[e2] = f2bf(v0) | (f2bf(v1) << 16);
    }
    if (it == 0) *(uint4*)(qnb + (size_t)t * 2048 + c0)          = *(uint4*)pk;
    else         *(uint4*)(knb + (size_t)t * 2048 + (c0 - 2048)) = *(uint4*)pk;
  }
}

// ---------------- delta-rule recurrence ----------------------------------
// grid 256 = (b, head, col-quarter). 4 waves own 32 k-rows each, split 2x
// in-wave (16 rows/lane). lane col = qtr*32 + (lane&31). state in VGPRs f32.
// k/q staged bf16 in LDS (16KB each), v bf16 from global, o written bf16.
#define CH 64
__global__ __launch_bounds__(256) void k_recur(const u16* __restrict__ qn,
                                               const u16* __restrict__ kn,
                                               const u16* __restrict__ vv,
                                               const float* __restrict__ g,
                                               const float* __restrict__ beta,
                                               u16* __restrict__ o) {
  __shared__ u16 sk[CH * 128];     // 16KB
  __shared__ u16 sq[CH * 128];     // 16KB
  __shared__ float seg[CH];
  __shared__ float sbe[CH];
  __shared__ float part1[2][4][32];
  __shared__ float part2[2][4][32];
  const int bid = blockIdx.x;
  const int b = bid >> 7, h = (bid >> 2) & 31, qtr = bid & 3;
  const int hk = h >> 1;
  const int tid = threadIdx.x, w = tid >> 6, lane = tid & 63;
  const int col = qtr * 32 + (lane & 31);
  const int r0 = w * 32 + (lane >> 5) * 16;
  float st[16] = {};
  const u16* kbase = kn + ((size_t)b * 2048 * 16 + hk) * 128;
  const u16* qbase = qn + ((size_t)b * 2048 * 16 + hk) * 128;
  const float* gbase = g + (size_t)b * 2048 * 32 + h;
  const float* bbase = beta + (size_t)b * 2048 * 32 + h;
  const u16* vbase = vv + ((size_t)b * 2048 * 32 + h) * 128 + col;
  u16* obase = o + ((size_t)b * 2048 * 32 + h) * 128 + col;

  for (int ch = 0; ch < 2048 / CH; ++ch) {
    const int s0 = ch * CH;
    __syncthreads();   // previous chunk fully consumed
#pragma unroll
    for (int j = 0; j < 4; ++j) {
      const int u = j * 4096 + w * 1024;     // wave-uniform LDS byte base
      const int y = u + lane * 16;           // this lane's linear byte
      const int stp = y >> 8;                // row (256B = 128 bf16 per row)
      const int d = (y & 255) >> 1;          // bf16 col (multiple of 8)
      const u16* gk = kbase + (size_t)(s0 + stp) * 2048 + d;
      __builtin_amdgcn_global_load_lds(AS1(gk), AS3((char*)sk + u), 16, 0, 0);
      const u16* gq = qbase + (size_t)(s0 + stp) * 2048 + d;
      __builtin_amdgcn_global_load_lds(AS1(gq), AS3((char*)sq + u), 16, 0, 0);
    }
    if (tid < CH) seg[tid] = expf(gbase[(size_t)(s0 + tid) * 32]);
    else if (tid < 2 * CH) sbe[tid - CH] = bbase[(size_t)(s0 + tid - CH) * 32];
    __syncthreads();   // staging complete (barrier drains vmcnt)
#pragma unroll 1
    for (int i = 0; i < CH; ++i) {
      const int s = s0 + i;
      const float eg = seg[i], bet = sbe[i];
      const float vval = bf2f(vbase[(size_t)s * 4096]);
      short8 kr0 = *(const short8*)(sk + i * 128 + r0);
      short8 kr1 = *(const short8*)(sk + i * 128 + r0 + 8);
      short8 qr0 = *(const short8*)(sq + i * 128 + r0);
      short8 qr1 = *(const short8*)(sq + i * 128 + r0 + 8);
      float kk[16], qq[16];
#pragma unroll
      for (int e = 0; e < 8; ++e) {
        kk[e] = bf2f((u16)kr0[e]); kk[8 + e] = bf2f((u16)kr1[e]);
        qq[e] = bf2f((u16)qr0[e]); qq[8 + e] = bf2f((u16)qr1[e]);
      }
      float kvp = 0.f;
#pragma unroll
      for (int tt = 0; tt < 16; ++tt) { st[tt] *= eg; kvp += kk[tt] * st[tt]; }
      kvp += __shfl_xor(kvp, 32);
      const int pb = i & 1;
      if (lane < 32) part1[pb][w][lane] = kvp;
      __syncthreads();
      const int c31 = lane & 31;
      float kv = part1[pb][0][c31] + part1[pb][1][c31] + part1[pb][2][c31] + part1[pb][3][c31];
      float delta = (vval - kv) * bet;
      float op = 0.f;
#pragma unroll
      for (int tt = 0; tt < 16; ++tt) { st[tt] += kk[tt] * delta; op += qq[tt] * st[tt]; }
      op += __shfl_xor(op, 32);
      if (lane < 32) part2[pb][w][lane] = op;
      __syncthreads();
      if (tid < 32) {
        float ov = part2[pb][0][tid] + part2[pb][1][tid] + part2[pb][2][tid] + part2[pb][3][tid];
        obase[(size_t)s * 4096] = (u16)f2bf(ov);
      }
    }
  }
}

// ---------------- gated RMSNorm epilogue (o bf16, z bf16) -> bf16 --------
__global__ __launch_bounds__(256) void k_epi(const u16* __restrict__ o,
                                             const u16* __restrict__ z,
                                             const float* __restrict__ nw,
                                             u16* __restrict__ og) {
  int gw = (blockIdx.x * 256 + threadIdx.x) >> 6;  // (token,head) row id
  int lane = threadIdx.x & 63;
  size_t base = (size_t)gw * 128;
  int d = lane * 2;
  unsigned xp = *(const unsigned*)(o + base + d);
  float x0 = bf2f((u16)(xp & 0xffff));
  float x1 = bf2f((u16)(xp >> 16));
  float ss = x0 * x0 + x1 * x1;
#pragma unroll
  for (int off = 1; off < 64; off <<= 1) ss += __shfl_xor(ss, off);
  float rms = rsqrtf(ss * (1.f / 128.f) + EPS);
  unsigned zp = *(const unsigned*)(z + base + d);
  float z0 = bf2f((u16)(zp & 0xffff));
  float z1 = bf2f((u16)(zp >> 16));
  float s0 = z0 / (1.f + expf(-z0));
  float s1 = z1 / (1.f + expf(-z1));
  float v0 = x0 * rms * nw[d] * s0;
  float v1 = x1 * rms * nw[d + 1] * s1;
  *(unsigned*)(og + base + d) = f2bf(v0) | (f2bf(v1) << 16);
}

extern "C" void kernel_launch(void* const* d_in, const int* in_sizes, int n_in,
                              void* d_out, int out_size, void* d_ws, size_t ws_size,
                              hipStream_t stream) {
  const float* hidden = (const float*)d_in[0];
  const float* Wqkv   = (const float*)d_in[1];
  const float* Wz     = (const float*)d_in[2];
  const float* Wa     = (const float*)d_in[3];
  const float* Wb     = (const float*)d_in[4];
  const float* convw  = (const float*)d_in[5];
  const float* Alog   = (const float*)d_in[6];
  const float* dtb    = (const float*)d_in[7];
  const float* nw     = (const float*)d_in[8];
  const float* Wout   = (const float*)d_in[9];

  // ---- workspace layout: 145 MB peak, heavily time-multiplexed ----------
  // d_out is written exactly once (final GEMM) — never used as scratch.
  char* ws = (char*)d_ws;
  size_t off = 0;
  auto take = [&](size_t b) { char* p = ws + off; off += (b + 255) & ~(size_t)255; return p; };
  u16* hb    = (u16*)take(8388608ull * 2);      // hidden bf16        16 MB (live: ..z GEMM)
  u16* wreg  = (u16*)take(16777216ull * 2);     // weight region      32 MB
  u16* qkvb  = (u16*)take(33554432ull * 2);     // qkv bf16           64 MB (live: ..conv)
  u16* vvb   = (u16*)take(16777216ull * 2);     // v bf16             32 MB (live: ..recur)
  float* gg  = (float*)take(131072ull * 4);
  float* bb  = (float*)take(131072ull * 4);
  // aliases (each target region is dead at write time):
  u16* qnb = wreg;                 // q-normed bf16 (Wqkv dead after qkv GEMM)
  u16* knb = wreg + 8388608;       // k-normed bf16
  u16* wzb = qkvb + 16777216;      // W_z bf16 in qkvb[32M..48M) (qkv dead after conv)
  u16* oob = qkvb;                 // o bf16 in qkvb[0..32M)
  u16* zb  = vvb;                  // z bf16 (v dead after recur)
  u16* wob = wreg;                 // W_out bf16 (qn dead after recur)
  u16* og  = qkvb + 16777216;      // gated o bf16 in qkvb[32M..64M) (Wz dead after z GEMM)

  k_cvt<<<8192, 256, 0, stream>>>(hidden, hb, 8388608);
  k_cvt<<<16384, 256, 0, stream>>>(Wqkv, wreg, 16777216);
  k_gemm_bt<true><<<2048, 256, 0, stream>>>(hb, wreg, qkvb, 4096, 8192, 2048);
  k_gates<<<4096, 64, 0, stream>>>(hidden, Wa, Wb, Alog, dtb, gg, bb);
  k_conv<<<4096, 256, 0, stream>>>(qkvb, convw, qnb, knb, vvb);
  k_cvt<<<8192, 256, 0, stream>>>(Wz, wzb, 8388608);
  k_recur<<<256, 256, 0, stream>>>(qnb, knb, vvb, gg, bb, oob);
  k_gemm_bt<true><<<1024, 256, 0, stream>>>(hb, wzb, zb, 4096, 4096, 2048);
  k_cvt<<<8192, 256, 0, stream>>>(Wout, wob, 8388608);
  k_epi<<<32768, 256, 0, stream>>>(oob, zb, nw, og);
  k_gemm_bt<false><<<512, 256, 0, stream>>>(og, wob, d_out, 4096, 2048, 4096);
}

// Round 6
// 1903.713 us; speedup vs baseline: 1.0483x; 1.0483x over previous
//
#include <hip/hip_runtime.h>
#include <math.h>

typedef unsigned short u16;
typedef __attribute__((ext_vector_type(8))) short short8;
typedef __attribute__((ext_vector_type(4))) float f32x4;

#define EPS 1e-6f
#define AS1(p) ((const __attribute__((address_space(1))) void*)(p))
#define AS3(p) ((__attribute__((address_space(3))) void*)(p))

__device__ __forceinline__ unsigned f2bf(float f) {
  union { float f; unsigned u; } v; v.f = f;
  return (v.u + 0x7fffu + ((v.u >> 16) & 1u)) >> 16;
}
__device__ __forceinline__ float bf2f(u16 u) {
  union { unsigned u; float f; } v; v.u = ((unsigned)u) << 16; return v.f;
}

// ---------------- f32 -> bf16 convert (packed, 4/thread) ----------------
__global__ void k_cvt(const float* __restrict__ in, u16* __restrict__ out, int n) {
  int i = (blockIdx.x * blockDim.x + threadIdx.x) * 4;
  if (i >= n) return;
  float4 v = *(const float4*)(in + i);
  uint2 p;
  p.x = f2bf(v.x) | (f2bf(v.y) << 16);
  p.y = f2bf(v.z) | (f2bf(v.w) << 16);
  *(uint2*)(out + i) = p;
}

// ---------------- bf16 GEMM: C[M,N] = A[M,K] * B[N,K]^T ------------------
// 128x128 tile, BK=32, 4 waves (2x2 of 64x64), mfma 16x16x32, global_load_lds
// width 16, both-sides XOR swizzle of 16B chunks: chunk ^= (row>>1)&3.
// OB: write bf16 output instead of f32.
template <bool OB>
__global__ __launch_bounds__(256) void k_gemm_bt(const u16* __restrict__ A,
                                                 const u16* __restrict__ Bm,
                                                 void* __restrict__ Cv,
                                                 int M, int N, int K) {
  __shared__ short sA[4096];   // [128 rows][32 k] bf16 = 8KB
  __shared__ short sB[4096];
  const int tid = threadIdx.x;
  const int w = tid >> 6, lane = tid & 63;
  const int nbt = N >> 7;
  const int nwg = (M >> 7) * nbt;
  int bid = blockIdx.x;
  { // bijective XCD swizzle (all grids here are %8==0)
    int q = nwg >> 3;
    bid = (bid & 7) * q + (bid >> 3);
  }
  const int mt = bid / nbt, nt = bid - mt * nbt;
  const int m0 = mt << 7, n0 = nt << 7;
  const int wr = (w >> 1) << 6, wc = (w & 1) << 6;

  f32x4 acc[4][4] = {};

  int rdA[4], rdB[4];
#pragma unroll
  for (int i = 0; i < 4; ++i) {
    int row = wr + i * 16 + (lane & 15);
    rdA[i] = row * 64 + (((lane >> 4) ^ ((row >> 1) & 3)) << 4);
    int col = wc + i * 16 + (lane & 15);
    rdB[i] = col * 64 + (((lane >> 4) ^ ((col >> 1) & 3)) << 4);
  }
  int srow[2], scol[2];
#pragma unroll
  for (int j = 0; j < 2; ++j) {
    int y = (w * 2 + j) * 1024 + lane * 16;    // linear LDS byte this lane fills
    int rr = y >> 6;
    int cs = ((y >> 4) & 3) ^ ((rr >> 1) & 3); // inverse-swizzled source chunk
    srow[j] = rr;
    scol[j] = cs * 8;
  }
  const int nk = K >> 5;
  for (int kt = 0; kt < nk; ++kt) {
    const int k0 = kt << 5;
#pragma unroll
    for (int j = 0; j < 2; ++j) {
      const int ca = (w * 2 + j) * 1024;
      const u16* ga = A + (size_t)(m0 + srow[j]) * K + (k0 + scol[j]);
      __builtin_amdgcn_global_load_lds(AS1(ga), AS3((char*)sA + ca), 16, 0, 0);
      const u16* gb = Bm + (size_t)(n0 + srow[j]) * K + (k0 + scol[j]);
      __builtin_amdgcn_global_load_lds(AS1(gb), AS3((char*)sB + ca), 16, 0, 0);
    }
    __syncthreads();
    short8 af[4], bfr[4];
#pragma unroll
    for (int i = 0; i < 4; ++i) af[i] = *(const short8*)((const char*)sA + rdA[i]);
#pragma unroll
    for (int i = 0; i < 4; ++i) bfr[i] = *(const short8*)((const char*)sB + rdB[i]);
#pragma unroll
    for (int i = 0; i < 4; ++i)
#pragma unroll
      for (int j = 0; j < 4; ++j)
        acc[i][j] = __builtin_amdgcn_mfma_f32_16x16x32_bf16(af[i], bfr[j], acc[i][j], 0, 0, 0);
    __syncthreads();
  }
#pragma unroll
  for (int i = 0; i < 4; ++i)
#pragma unroll
    for (int j = 0; j < 4; ++j)
#pragma unroll
      for (int qe = 0; qe < 4; ++qe) {
        int mrow = m0 + wr + i * 16 + ((lane >> 4) << 2) + qe;
        int ncol = n0 + wc + j * 16 + (lane & 15);
        if (OB) ((u16*)Cv)[(size_t)mrow * N + ncol] = (u16)f2bf(acc[i][j][qe]);
        else    ((float*)Cv)[(size_t)mrow * N + ncol] = acc[i][j][qe];
      }
}

// ---------------- gates: a,b projections -> g, beta ----------------------
__global__ void k_gates(const float* __restrict__ hidden, const float* __restrict__ Wa,
                        const float* __restrict__ Wb, const float* __restrict__ Alog,
                        const float* __restrict__ dtb, float* __restrict__ g,
                        float* __restrict__ beta) {
  int t = blockIdx.x;              // token 0..4095
  int tid = threadIdx.x;           // 64: 0..31 -> a/g, 32..63 -> b/beta
  int h = tid & 31;
  const float4* h4 = (const float4*)(hidden + (size_t)t * 2048);
  const float4* w4 = (const float4*)((tid < 32 ? Wa : Wb) + (size_t)h * 2048);
  float acc = 0.f;
  for (int i = 0; i < 512; ++i) {
    float4 x = h4[i], y = w4[i];
    acc += x.x * y.x + x.y * y.y + x.z * y.z + x.w * y.w;
  }
  if (tid < 32) {
    float x = acc + dtb[h];
    float sp = x > 20.f ? x : log1pf(expf(x));
    g[t * 32 + h] = -expf(Alog[h]) * sp;
  } else {
    beta[t * 32 + h] = 1.f / (1.f + expf(-acc));
  }
}

// ---------------- causal conv(4) + SiLU + split + l2norm -----------------
// qkv bf16 in, qn/kn/vv bf16 out (packed). 8 channels per thread.
__global__ __launch_bounds__(256) void k_conv(const u16* __restrict__ qkv,
                                              const float* __restrict__ convw,
                                              u16* __restrict__ qnb, u16* __restrict__ knb,
                                              u16* __restrict__ vvb) {
  __shared__ float mix[4096];
  __shared__ float red[32][8];
  __shared__ float fac[32];
  const int t = blockIdx.x;
  const int s = t & 2047;
  const int tid = threadIdx.x;
  const u16* base = qkv + (size_t)t * 8192;
  // q,k channels 0..4095 -> LDS (need norms)
  for (int it = 0; it < 2; ++it) {
    int c0 = (it * 256 + tid) * 8;
    short8 x0 = *(const short8*)(base + c0);
    short8 x1 = (short8)0, x2 = (short8)0, x3 = (short8)0;
    if (s >= 1) x1 = *(const short8*)(base + c0 - 8192);
    if (s >= 2) x2 = *(const short8*)(base + c0 - 16384);
    if (s >= 3) x3 = *(const short8*)(base + c0 - 24576);
#pragma unroll
    for (int e = 0; e < 8; ++e) {
      int c = c0 + e;
      float4 wv = *(const float4*)(convw + c * 4);
      float a = bf2f((u16)x0[e]) * wv.w + bf2f((u16)x1[e]) * wv.z
              + bf2f((u16)x2[e]) * wv.y + bf2f((u16)x3[e]) * wv.x;
      mix[c] = a / (1.f + expf(-a));     // SiLU
    }
  }
  // v channels 4096..8191 -> straight to global (bf16 packed)
  for (int it = 0; it < 2; ++it) {
    int c0 = 4096 + (it * 256 + tid) * 8;
    short8 x0 = *(const short8*)(base + c0);
    short8 x1 = (short8)0, x2 = (short8)0, x3 = (short8)0;
    if (s >= 1) x1 = *(const short8*)(base + c0 - 8192);
    if (s >= 2) x2 = *(const short8*)(base + c0 - 16384);
    if (s >= 3) x3 = *(const short8*)(base + c0 - 24576);
    unsigned pk[4];
#pragma unroll
    for (int e2 = 0; e2 < 4; ++e2) {
      float vs[2];
#pragma unroll
      for (int u = 0; u < 2; ++u) {
        int e = e2 * 2 + u;
        float4 wv = *(const float4*)(convw + (c0 + e) * 4);
        float a = bf2f((u16)x0[e]) * wv.w + bf2f((u16)x1[e]) * wv.z
                + bf2f((u16)x2[e]) * wv.y + bf2f((u16)x3[e]) * wv.x;
        vs[u] = a / (1.f + expf(-a));
      }
      pk[e2] = f2bf(vs[0]) | (f2bf(vs[1]) << 16);
    }
    *(uint4*)(vvb + (size_t)t * 4096 + (c0 - 4096)) = *(uint4*)pk;
  }
  __syncthreads();
  { // per-head sumsq (32 head-slots x 8 partials of 16)
    int hh = tid >> 3, p = tid & 7;
    float ss2 = 0.f;
#pragma unroll
    for (int e = 0; e < 16; ++e) { float x = mix[hh * 128 + p * 16 + e]; ss2 += x * x; }
    red[hh][p] = ss2;
  }
  __syncthreads();
  if (tid < 32) {
    float ss2 = 0.f;
#pragma unroll
    for (int p = 0; p < 8; ++p) ss2 += red[tid][p];
    float inv = 1.f / fmaxf(sqrtf(ss2), EPS);
    if (tid < 16) inv *= 0.08838834764831845f;   // * DK^-0.5 for q heads
    fac[tid] = inv;
  }
  __syncthreads();
  // q -> qnb (it=0), k -> knb (it=1), bf16 packed
  for (int it = 0; it < 2; ++it) {
    int c0 = (it * 256 + tid) * 8;          // 0..2040 then 2048..4088
    float f = fac[c0 >> 7];
    unsigned pk[4];
#pragma unroll
    for (int e2 = 0; e2 < 4; ++e2) {
      float v0 = mix[c0 + e2 * 2] * f;
      float v1 = mix[c0 + e2 * 2 + 1] * f;
      pk[e2] = f2bf(v0) | (f2bf(v1) << 16);
    }
    if (it == 0) *(uint4*)(qnb + (size_t)t * 2048 + c0)          = *(uint4*)pk;
    else         *(uint4*)(knb + (size_t)t * 2048 + (c0 - 2048)) = *(uint4*)pk;
  }
}

// ---------------- delta-rule recurrence (wave-local, barrier-free) -------
// grid 1024 = 64 (b,h) x 16 col-groups. ONE wave per block. Lane = (oct,ci):
// owns k-rows [oct*16, oct*16+16) x column (cg*8 + ci). k-reduction = 3x
// shfl_xor(8,16,32) -- no barriers, no cross-wave LDS. k/q/v/g/beta double-
// buffer staged per 32-step chunk via global_load_lds. 34KB LDS -> 4 blk/CU.
#define RCH 32
__global__ __launch_bounds__(64) void k_recur(const u16* __restrict__ qn,
                                              const u16* __restrict__ kn,
                                              const u16* __restrict__ vv,
                                              const float* __restrict__ g,
                                              const float* __restrict__ beta,
                                              u16* __restrict__ o) {
  __shared__ u16 sk[2][RCH * 128];   // 16KB
  __shared__ u16 sq[2][RCH * 128];   // 16KB
  __shared__ u16 sv[2][RCH * 8];     // 1KB
  __shared__ float sG[2][RCH];
  __shared__ float sBt[2][RCH];
  int bid = blockIdx.x;
  const int swz = (bid & 7) * 128 + (bid >> 3);  // XCD swizzle: co-locate sharers
  const int b = swz >> 9, h = (swz >> 4) & 31, cg = swz & 15;
  const int hk = h >> 1, c0 = cg * 8;
  const int lane = threadIdx.x & 63;
  const int oct = lane >> 3, ci = lane & 7;
  const u16* kbase = kn + ((size_t)b * 2048 * 16 + hk) * 128;
  const u16* qbase = qn + ((size_t)b * 2048 * 16 + hk) * 128;
  const float* gbase = g + (size_t)b * 2048 * 32 + h;
  const float* bbase = beta + (size_t)b * 2048 * 32 + h;
  const u16* vbase = vv + ((size_t)b * 2048 * 32 + h) * 128 + c0;
  u16* obase = o + ((size_t)b * 2048 * 32 + h) * 128 + c0 + ci;

  float st[16] = {};   // k-rows oct*16.. x col (c0+ci)

  auto stage = [&](int s0, int ib) {
#pragma unroll
    for (int j = 0; j < 8; ++j) {
      const int y = j * 1024 + lane * 16;   // byte in 8KB chunk image
      const int stp = y >> 8, dc = (y & 255) >> 1;
      __builtin_amdgcn_global_load_lds(AS1(kbase + (size_t)(s0 + stp) * 2048 + dc),
                                       AS3((char*)sk[ib] + j * 1024), 16, 0, 0);
      __builtin_amdgcn_global_load_lds(AS1(qbase + (size_t)(s0 + stp) * 2048 + dc),
                                       AS3((char*)sq[ib] + j * 1024), 16, 0, 0);
    }
    if (lane < RCH) {
      __builtin_amdgcn_global_load_lds(AS1(vbase + (size_t)(s0 + lane) * 4096),
                                       AS3((char*)sv[ib]), 16, 0, 0);
      sG[ib][lane] = expf(gbase[(size_t)(s0 + lane) * 32]);
    } else {
      sBt[ib][lane - RCH] = bbase[(size_t)(s0 + lane - RCH) * 32];
    }
  };

  stage(0, 0);
  __syncthreads();   // 1-wave block: this is just a waitcnt
  for (int ch = 0; ch < 2048 / RCH; ++ch) {
    const int ib = ch & 1;
    if (ch + 1 < 2048 / RCH) stage((ch + 1) * RCH, ib ^ 1);
#pragma unroll 4
    for (int i = 0; i < RCH; ++i) {
      const int s = ch * RCH + i;
      const float eg = sG[ib][i], bet = sBt[ib][i];
      const float vval = bf2f(sv[ib][i * 8 + ci]);
      const u16* kr = &sk[ib][i * 128 + oct * 16];
      const u16* qr = &sq[ib][i * 128 + oct * 16];
      short8 k0 = *(const short8*)kr, k1 = *(const short8*)(kr + 8);
      short8 q0 = *(const short8*)qr, q1 = *(const short8*)(qr + 8);
      float kk[16], qq[16];
#pragma unroll
      for (int e = 0; e < 8; ++e) {
        kk[e] = bf2f((u16)k0[e]); kk[8 + e] = bf2f((u16)k1[e]);
        qq[e] = bf2f((u16)q0[e]); qq[8 + e] = bf2f((u16)q1[e]);
      }
      float a0 = 0.f, a1 = 0.f, a2 = 0.f, a3 = 0.f;
#pragma unroll
      for (int t4 = 0; t4 < 16; t4 += 4) {
        st[t4 + 0] *= eg; a0 += kk[t4 + 0] * st[t4 + 0];
        st[t4 + 1] *= eg; a1 += kk[t4 + 1] * st[t4 + 1];
        st[t4 + 2] *= eg; a2 += kk[t4 + 2] * st[t4 + 2];
        st[t4 + 3] *= eg; a3 += kk[t4 + 3] * st[t4 + 3];
      }
      float kv = (a0 + a1) + (a2 + a3);
      kv += __shfl_xor(kv, 8);
      kv += __shfl_xor(kv, 16);
      kv += __shfl_xor(kv, 32);
      const float delta = (vval - kv) * bet;
      float o0 = 0.f, o1 = 0.f, o2 = 0.f, o3 = 0.f;
#pragma unroll
      for (int t4 = 0; t4 < 16; t4 += 4) {
        st[t4 + 0] += kk[t4 + 0] * delta; o0 += qq[t4 + 0] * st[t4 + 0];
        st[t4 + 1] += kk[t4 + 1] * delta; o1 += qq[t4 + 1] * st[t4 + 1];
        st[t4 + 2] += kk[t4 + 2] * delta; o2 += qq[t4 + 2] * st[t4 + 2];
        st[t4 + 3] += kk[t4 + 3] * delta; o3 += qq[t4 + 3] * st[t4 + 3];
      }
      float op = (o0 + o1) + (o2 + o3);
      op += __shfl_xor(op, 8);
      op += __shfl_xor(op, 16);
      op += __shfl_xor(op, 32);
      if (oct == 0) obase[(size_t)s * 4096] = (u16)f2bf(op);
    }
    __syncthreads();   // waitcnt: staging of next chunk complete
  }
}

// ---------------- gated RMSNorm epilogue (o bf16, z bf16) -> bf16 --------
__global__ __launch_bounds__(256) void k_epi(const u16* __restrict__ o,
                                             const u16* __restrict__ z,
                                             const float* __restrict__ nw,
                                             u16* __restrict__ og) {
  int gw = (blockIdx.x * 256 + threadIdx.x) >> 6;  // (token,head) row id
  int lane = threadIdx.x & 63;
  size_t base = (size_t)gw * 128;
  int d = lane * 2;
  unsigned xp = *(const unsigned*)(o + base + d);
  float x0 = bf2f((u16)(xp & 0xffff));
  float x1 = bf2f((u16)(xp >> 16));
  float ss = x0 * x0 + x1 * x1;
#pragma unroll
  for (int off = 1; off < 64; off <<= 1) ss += __shfl_xor(ss, off);
  float rms = rsqrtf(ss * (1.f / 128.f) + EPS);
  unsigned zp = *(const unsigned*)(z + base + d);
  float z0 = bf2f((u16)(zp & 0xffff));
  float z1 = bf2f((u16)(zp >> 16));
  float s0 = z0 / (1.f + expf(-z0));
  float s1 = z1 / (1.f + expf(-z1));
  float v0 = x0 * rms * nw[d] * s0;
  float v1 = x1 * rms * nw[d + 1] * s1;
  *(unsigned*)(og + base + d) = f2bf(v0) | (f2bf(v1) << 16);
}

extern "C" void kernel_launch(void* const* d_in, const int* in_sizes, int n_in,
                              void* d_out, int out_size, void* d_ws, size_t ws_size,
                              hipStream_t stream) {
  const float* hidden = (const float*)d_in[0];
  const float* Wqkv   = (const float*)d_in[1];
  const float* Wz     = (const float*)d_in[2];
  const float* Wa     = (const float*)d_in[3];
  const float* Wb     = (const float*)d_in[4];
  const float* convw  = (const float*)d_in[5];
  const float* Alog   = (const float*)d_in[6];
  const float* dtb    = (const float*)d_in[7];
  const float* nw     = (const float*)d_in[8];
  const float* Wout   = (const float*)d_in[9];

  // ---- workspace layout: 145 MB peak, heavily time-multiplexed ----------
  // d_out is written exactly once (final GEMM) — never used as scratch.
  char* ws = (char*)d_ws;
  size_t off = 0;
  auto take = [&](size_t b) { char* p = ws + off; off += (b + 255) & ~(size_t)255; return p; };
  u16* hb    = (u16*)take(8388608ull * 2);      // hidden bf16        16 MB (live: ..z GEMM)
  u16* wreg  = (u16*)take(16777216ull * 2);     // weight region      32 MB
  u16* qkvb  = (u16*)take(33554432ull * 2);     // qkv bf16           64 MB (live: ..conv)
  u16* vvb   = (u16*)take(16777216ull * 2);     // v bf16             32 MB (live: ..recur)
  float* gg  = (float*)take(131072ull * 4);
  float* bb  = (float*)take(131072ull * 4);
  // aliases (each target region is dead at write time):
  u16* qnb = wreg;                 // q-normed bf16 (Wqkv dead after qkv GEMM)
  u16* knb = wreg + 8388608;       // k-normed bf16
  u16* wzb = qkvb + 16777216;      // W_z bf16 in qkvb[32M..48M) (qkv dead after conv)
  u16* oob = qkvb;                 // o bf16 in qkvb[0..32M)
  u16* zb  = vvb;                  // z bf16 (v dead after recur)
  u16* wob = wreg;                 // W_out bf16 (qn dead after recur)
  u16* og  = qkvb + 16777216;      // gated o bf16 in qkvb[32M..64M) (Wz dead after z GEMM)

  k_cvt<<<8192, 256, 0, stream>>>(hidden, hb, 8388608);
  k_cvt<<<16384, 256, 0, stream>>>(Wqkv, wreg, 16777216);
  k_gemm_bt<true><<<2048, 256, 0, stream>>>(hb, wreg, qkvb, 4096, 8192, 2048);
  k_gates<<<4096, 64, 0, stream>>>(hidden, Wa, Wb, Alog, dtb, gg, bb);
  k_conv<<<4096, 256, 0, stream>>>(qkvb, convw, qnb, knb, vvb);
  k_cvt<<<8192, 256, 0, stream>>>(Wz, wzb, 8388608);
  k_recur<<<1024, 64, 0, stream>>>(qnb, knb, vvb, gg, bb, oob);
  k_gemm_bt<true><<<1024, 256, 0, stream>>>(hb, wzb, zb, 4096, 4096, 2048);
  k_cvt<<<8192, 256, 0, stream>>>(Wout, wob, 8388608);
  k_epi<<<32768, 256, 0, stream>>>(oob, zb, nw, og);
  k_gemm_bt<false><<<512, 256, 0, stream>>>(og, wob, d_out, 4096, 2048, 4096);
}